// Round 1
// baseline (8384.214 us; speedup 1.0000x reference)
//
#include <hip/hip_runtime.h>
#include <math.h>

// Problem constants
#define BB 64      // batch
#define SS 512     // seq
#define EE 256     // embed
#define HH 512     // hidden

// ---------------------------------------------------------------------------
// Stage plan (all f32 for round-1 correctness; threshold 1.33e-3 makes bf16
// in the recurrence risky -- test precision drops in later rounds):
//   1. transpose W_hh0, W_hh1 -> WT (so rec kernel weight loads coalesce)
//   2. xp0 = emb[x] @ W_ih0^T + b_ih0 + b_hh0      (tiled GEMM w/ gather)
//   3. layer-0 recurrence (batch-split, no inter-block sync) -> out0
//   4. xp1 = out0 @ W_ih1^T + b_ih1 + b_hh1        (tiled GEMM, overwrites xp)
//   5. layer-1 recurrence -> pooled (mean over time accumulated in regs)
//   6. out = pooled @ W_out^T + b_out
// ---------------------------------------------------------------------------

// W transpose: WT[j][i] = W[i][j], 512x512
__global__ void transpose512(const float* __restrict__ in, float* __restrict__ out) {
  __shared__ float tile[32][33];
  int bx = blockIdx.x * 32, by = blockIdx.y * 32;
  int x = threadIdx.x, y0 = threadIdx.y;  // block (32,8)
  for (int dy = 0; dy < 32; dy += 8)
    tile[y0 + dy][x] = in[(size_t)(by + y0 + dy) * HH + bx + x];
  __syncthreads();
  for (int dy = 0; dy < 32; dy += 8)
    out[(size_t)(bx + y0 + dy) * HH + by + x] = tile[x][y0 + dy];
}

// Tiled GEMM: C[m][n] = sum_k A[m][k] * Wn[n][k] + bias1[n] + bias2[n]
// A is either gathered from emb via xidx (GATHER) or a plain row-major matrix.
// M = 32768, N = 512, K template. Tile 64x64, BK=32, 256 threads, 4x4 micro.
template <int K, bool GATHER>
__global__ __launch_bounds__(256) void xp_gemm(
    const float* __restrict__ Asrc, const int* __restrict__ xidx,
    const float* __restrict__ emb, const float* __restrict__ Wn,
    const float* __restrict__ bias1, const float* __restrict__ bias2,
    float* __restrict__ C) {
  const int tid = threadIdx.x;
  const int m0 = blockIdx.x * 64;
  const int n0 = blockIdx.y * 64;
  __shared__ alignas(16) float As[32][68];
  __shared__ alignas(16) float Bs[32][68];
  __shared__ int xs[64];
  if (GATHER) {
    if (tid < 64) xs[tid] = xidx[m0 + tid];
    __syncthreads();
  }
  float acc[4][4] = {};
  const int ty = tid >> 4, tx = tid & 15;
  const int row = tid >> 2;          // 0..63
  const int kc = (tid & 3) * 8;      // 0,8,16,24

  for (int k0 = 0; k0 < K; k0 += 32) {
    const float* ap;
    if (GATHER) ap = emb + (size_t)xs[row] * EE + (k0 + kc);
    else        ap = Asrc + (size_t)(m0 + row) * K + (k0 + kc);
    float4 av0 = *(const float4*)ap;
    float4 av1 = *(const float4*)(ap + 4);
    const float* bp = Wn + (size_t)(n0 + row) * K + (k0 + kc);
    float4 bv0 = *(const float4*)bp;
    float4 bv1 = *(const float4*)(bp + 4);
    __syncthreads();  // previous tile's compute reads done
    As[kc + 0][row] = av0.x; As[kc + 1][row] = av0.y;
    As[kc + 2][row] = av0.z; As[kc + 3][row] = av0.w;
    As[kc + 4][row] = av1.x; As[kc + 5][row] = av1.y;
    As[kc + 6][row] = av1.z; As[kc + 7][row] = av1.w;
    Bs[kc + 0][row] = bv0.x; Bs[kc + 1][row] = bv0.y;
    Bs[kc + 2][row] = bv0.z; Bs[kc + 3][row] = bv0.w;
    Bs[kc + 4][row] = bv1.x; Bs[kc + 5][row] = bv1.y;
    Bs[kc + 6][row] = bv1.z; Bs[kc + 7][row] = bv1.w;
    __syncthreads();
#pragma unroll 8
    for (int k = 0; k < 32; ++k) {
      float4 av = *(const float4*)&As[k][ty * 4];
      float4 bv = *(const float4*)&Bs[k][tx * 4];
      acc[0][0] += av.x * bv.x; acc[0][1] += av.x * bv.y;
      acc[0][2] += av.x * bv.z; acc[0][3] += av.x * bv.w;
      acc[1][0] += av.y * bv.x; acc[1][1] += av.y * bv.y;
      acc[1][2] += av.y * bv.z; acc[1][3] += av.y * bv.w;
      acc[2][0] += av.z * bv.x; acc[2][1] += av.z * bv.y;
      acc[2][2] += av.z * bv.z; acc[2][3] += av.z * bv.w;
      acc[3][0] += av.w * bv.x; acc[3][1] += av.w * bv.y;
      acc[3][2] += av.w * bv.z; acc[3][3] += av.w * bv.w;
    }
  }
  float bj[4];
#pragma unroll
  for (int j = 0; j < 4; ++j) {
    int n = n0 + tx * 4 + j;
    bj[j] = bias1[n] + bias2[n];
  }
#pragma unroll
  for (int i = 0; i < 4; ++i) {
    float4 cv = make_float4(acc[i][0] + bj[0], acc[i][1] + bj[1],
                            acc[i][2] + bj[2], acc[i][3] + bj[3]);
    *(float4*)&C[(size_t)(m0 + ty * 4 + i) * HH + n0 + tx * 4] = cv;
  }
}

// Recurrence: per block 2 batches, 1024 threads.
// Thread (g = tid>>7 in [0,8), t = tid&127): partial dot for outputs
// 4t..4t+3 over j in [64g, 64g+64), for both batches.  WT[j][i] = W_hh[i][j].
template <bool WRITE_OUT>
__global__ __launch_bounds__(1024) void rec_kernel(
    const float* __restrict__ xp,   // [B][S][H]
    const float* __restrict__ WT,   // [H][H] transposed
    float* __restrict__ outp,       // [B][S][H]  (layer 0)
    float* __restrict__ pooled) {   // [B][H]     (layer 1)
  const int tid = threadIdx.x;
  const int g = tid >> 7;
  const int tt = tid & 127;
  const int b0 = blockIdx.x * 2;
  __shared__ alignas(16) float hs[2][HH];
  __shared__ alignas(16) float part[8][2][HH];
  if (tid < HH) { hs[0][tid] = 0.f; hs[1][tid] = 0.f; }
  __syncthreads();

  const int bb = tid >> 9;       // finalize mapping: batch select
  const int oi = tid & 511;      // finalize output index
  float pacc = 0.f;
  const float* wp = WT + (size_t)(g * 64) * HH + tt * 4;

  for (int t = 0; t < SS; ++t) {
    float4 a0 = make_float4(0.f, 0.f, 0.f, 0.f);
    float4 a1 = make_float4(0.f, 0.f, 0.f, 0.f);
#pragma unroll 4
    for (int jj = 0; jj < 16; ++jj) {
      float4 h0v = *(const float4*)&hs[0][g * 64 + jj * 4];
      float4 h1v = *(const float4*)&hs[1][g * 64 + jj * 4];
      float4 w0 = *(const float4*)(wp + (size_t)(jj * 4 + 0) * HH);
      float4 w1 = *(const float4*)(wp + (size_t)(jj * 4 + 1) * HH);
      float4 w2 = *(const float4*)(wp + (size_t)(jj * 4 + 2) * HH);
      float4 w3 = *(const float4*)(wp + (size_t)(jj * 4 + 3) * HH);
      a0.x += w0.x * h0v.x; a0.y += w0.y * h0v.x; a0.z += w0.z * h0v.x; a0.w += w0.w * h0v.x;
      a1.x += w0.x * h1v.x; a1.y += w0.y * h1v.x; a1.z += w0.z * h1v.x; a1.w += w0.w * h1v.x;
      a0.x += w1.x * h0v.y; a0.y += w1.y * h0v.y; a0.z += w1.z * h0v.y; a0.w += w1.w * h0v.y;
      a1.x += w1.x * h1v.y; a1.y += w1.y * h1v.y; a1.z += w1.z * h1v.y; a1.w += w1.w * h1v.y;
      a0.x += w2.x * h0v.z; a0.y += w2.y * h0v.z; a0.z += w2.z * h0v.z; a0.w += w2.w * h0v.z;
      a1.x += w2.x * h1v.z; a1.y += w2.y * h1v.z; a1.z += w2.z * h1v.z; a1.w += w2.w * h1v.z;
      a0.x += w3.x * h0v.w; a0.y += w3.y * h0v.w; a0.z += w3.z * h0v.w; a0.w += w3.w * h0v.w;
      a1.x += w3.x * h1v.w; a1.y += w3.y * h1v.w; a1.z += w3.z * h1v.w; a1.w += w3.w * h1v.w;
    }
    *(float4*)&part[g][0][tt * 4] = a0;
    *(float4*)&part[g][1][tt * 4] = a1;
    __syncthreads();
    // finalize: thread -> (bb, oi)
    float v = xp[(size_t)(b0 + bb) * (SS * HH) + (size_t)t * HH + oi];
#pragma unroll
    for (int gg = 0; gg < 8; ++gg) v += part[gg][bb][oi];
    float nh = tanhf(v);
    hs[bb][oi] = nh;  // safe: all j-loop reads of hs completed before barrier
    if (WRITE_OUT)
      outp[(size_t)(b0 + bb) * (SS * HH) + (size_t)t * HH + oi] = nh;
    else
      pacc += nh;
    __syncthreads();
  }
  if (!WRITE_OUT)
    pooled[(size_t)(b0 + bb) * HH + oi] = pacc * (1.0f / SS);
}

// Final head: out[b][c] = sum_k pooled[b][k] * W_out[c][k] + b_out[c]
__global__ void out_kernel(const float* __restrict__ pooled,
                           const float* __restrict__ W_out,
                           const float* __restrict__ b_out,
                           float* __restrict__ out) {
  int tid = threadIdx.x;
  if (tid >= BB * 2) return;
  int b = tid >> 1, c = tid & 1;
  float acc = b_out[c];
  for (int k = 0; k < HH; ++k)
    acc += pooled[(size_t)b * HH + k] * W_out[(size_t)c * HH + k];
  out[(size_t)b * 2 + c] = acc;
}

extern "C" void kernel_launch(void* const* d_in, const int* in_sizes, int n_in,
                              void* d_out, int out_size, void* d_ws, size_t ws_size,
                              hipStream_t stream) {
  const int*   x     = (const int*)d_in[0];
  const float* emb   = (const float*)d_in[1];
  const float* W_ih0 = (const float*)d_in[2];
  const float* W_hh0 = (const float*)d_in[3];
  const float* b_ih0 = (const float*)d_in[4];
  const float* b_hh0 = (const float*)d_in[5];
  const float* W_ih1 = (const float*)d_in[6];
  const float* W_hh1 = (const float*)d_in[7];
  const float* b_ih1 = (const float*)d_in[8];
  const float* b_hh1 = (const float*)d_in[9];
  const float* W_out = (const float*)d_in[10];
  const float* b_out = (const float*)d_in[11];

  float* ws = (float*)d_ws;
  const size_t NBSH = (size_t)BB * SS * HH;  // 16777216
  float* xp     = ws;                 // xp0, later xp1 (64 MB)
  float* out0   = ws + NBSH;          // layer-0 output (64 MB)
  float* WT0    = ws + 2 * NBSH;      // 1 MB
  float* WT1    = WT0 + HH * HH;      // 1 MB
  float* pooled = WT1 + HH * HH;      // 128 KB

  dim3 tb(32, 8), tg(16, 16);
  transpose512<<<tg, tb, 0, stream>>>(W_hh0, WT0);
  transpose512<<<tg, tb, 0, stream>>>(W_hh1, WT1);

  dim3 gg(512, 8);
  xp_gemm<EE, true><<<gg, 256, 0, stream>>>(nullptr, x, emb, W_ih0, b_ih0, b_hh0, xp);
  rec_kernel<true><<<32, 1024, 0, stream>>>(xp, WT0, out0, nullptr);
  xp_gemm<HH, false><<<gg, 256, 0, stream>>>(out0, nullptr, nullptr, W_ih1, b_ih1, b_hh1, xp);
  rec_kernel<false><<<32, 1024, 0, stream>>>(xp, WT1, nullptr, pooled);
  out_kernel<<<1, 128, 0, stream>>>(pooled, W_out, b_out, (float*)d_out);
}